// Round 1
// baseline (541.411 us; speedup 1.0000x reference)
//
#include <hip/hip_runtime.h>
#include <hip/hip_bf16.h>
#include <math.h>

// Problem dims (fixed by setup_inputs): B=4, S=512, T=256, H=1024, V=32000
#define TILE 64
#define BK 16

// -------- Kernel 1: enc = tanh(encoder_outputs @ W_proj + b_proj) --------
// A: [M,K] row-major, W: [K,N] row-major, C: [M,N]
__global__ __launch_bounds__(256) void gemm_tanh(const float* __restrict__ A,
                                                 const float* __restrict__ W,
                                                 const float* __restrict__ bias,
                                                 float* __restrict__ C,
                                                 int M, int N, int K) {
    __shared__ float As[BK][TILE + 1];
    __shared__ float Bs[BK][TILE + 1];
    const int tid = threadIdx.x;
    const int tx = tid % 16;           // col group
    const int ty = tid / 16;           // row group
    const int row0 = blockIdx.y * TILE;
    const int col0 = blockIdx.x * TILE;

    float acc[4][4] = {};

    for (int k0 = 0; k0 < K; k0 += BK) {
        // A tile: 64 rows x BK cols
        #pragma unroll
        for (int i = tid; i < TILE * BK; i += 256) {
            int r = i / BK, kk = i % BK;
            As[kk][r] = A[(size_t)(row0 + r) * K + k0 + kk];
        }
        // B tile: BK rows x 64 cols
        #pragma unroll
        for (int i = tid; i < TILE * BK; i += 256) {
            int kk = i / TILE, c = i % TILE;
            Bs[kk][c] = W[(size_t)(k0 + kk) * N + col0 + c];
        }
        __syncthreads();
        #pragma unroll
        for (int kk = 0; kk < BK; ++kk) {
            float a[4], bb[4];
            #pragma unroll
            for (int i = 0; i < 4; ++i) a[i] = As[kk][ty * 4 + i];
            #pragma unroll
            for (int j = 0; j < 4; ++j) bb[j] = Bs[kk][tx * 4 + j];
            #pragma unroll
            for (int i = 0; i < 4; ++i)
                #pragma unroll
                for (int j = 0; j < 4; ++j)
                    acc[i][j] += a[i] * bb[j];
        }
        __syncthreads();
    }

    #pragma unroll
    for (int i = 0; i < 4; ++i) {
        int r = row0 + ty * 4 + i;
        #pragma unroll
        for (int j = 0; j < 4; ++j) {
            int c = col0 + tx * 4 + j;
            C[(size_t)r * N + c] = tanhf(acc[i][j] + bias[c]);
        }
    }
}

// -------- Kernel 2: scores[b] = dec[b] @ enc[b]^T + input_bias[b] --------
// dec: [B,T,H], enc: [B,S,H], scores: [B,T,S]
__global__ __launch_bounds__(256) void gemm_nt_bias(const float* __restrict__ dec,
                                                    const float* __restrict__ enc,
                                                    const float* __restrict__ ibias,
                                                    float* __restrict__ scores,
                                                    int T, int S, int H) {
    const int b = blockIdx.z;
    const float* A = dec + (size_t)b * T * H;
    const float* Bm = enc + (size_t)b * S * H;
    const float* bi = ibias + (size_t)b * S;
    float* C = scores + (size_t)b * T * S;

    __shared__ float As[BK][TILE + 1];
    __shared__ float Bs[BK][TILE + 1];
    const int tid = threadIdx.x;
    const int tx = tid % 16;
    const int ty = tid / 16;
    const int row0 = blockIdx.y * TILE;  // t dim
    const int col0 = blockIdx.x * TILE;  // s dim

    float acc[4][4] = {};

    for (int k0 = 0; k0 < H; k0 += BK) {
        #pragma unroll
        for (int i = tid; i < TILE * BK; i += 256) {
            int r = i / BK, kk = i % BK;
            As[kk][r] = A[(size_t)(row0 + r) * H + k0 + kk];
        }
        // B^T tile: Bs[kk][c] = enc[col0+c, k0+kk]
        #pragma unroll
        for (int i = tid; i < TILE * BK; i += 256) {
            int c = i / BK, kk = i % BK;
            Bs[kk][c] = Bm[(size_t)(col0 + c) * H + k0 + kk];
        }
        __syncthreads();
        #pragma unroll
        for (int kk = 0; kk < BK; ++kk) {
            float a[4], bb[4];
            #pragma unroll
            for (int i = 0; i < 4; ++i) a[i] = As[kk][ty * 4 + i];
            #pragma unroll
            for (int j = 0; j < 4; ++j) bb[j] = Bs[kk][tx * 4 + j];
            #pragma unroll
            for (int i = 0; i < 4; ++i)
                #pragma unroll
                for (int j = 0; j < 4; ++j)
                    acc[i][j] += a[i] * bb[j];
        }
        __syncthreads();
    }

    #pragma unroll
    for (int i = 0; i < 4; ++i) {
        int r = row0 + ty * 4 + i;
        #pragma unroll
        for (int j = 0; j < 4; ++j) {
            int c = col0 + tx * 4 + j;
            C[(size_t)r * S + c] = acc[i][j] + bi[c];
        }
    }
}

// -------- Kernel 3: per (b,t) row: softmax over S then scatter-add --------
__inline__ __device__ float waveReduceMax(float v) {
    #pragma unroll
    for (int off = 32; off > 0; off >>= 1) v = fmaxf(v, __shfl_down(v, off));
    return v;
}
__inline__ __device__ float waveReduceSum(float v) {
    #pragma unroll
    for (int off = 32; off > 0; off >>= 1) v += __shfl_down(v, off);
    return v;
}

__global__ __launch_bounds__(256) void softmax_scatter(const float* __restrict__ scores,
                                                       const int* __restrict__ tokens,
                                                       float* __restrict__ out,
                                                       int T, int S, int V) {
    const int row = blockIdx.x;        // b*T + t
    const int b = row / T;
    const float* sc = scores + (size_t)row * S;
    const int* tok = tokens + (size_t)b * S;
    float* o = out + (size_t)row * V;

    __shared__ float red[4];
    const int tid = threadIdx.x;
    const int wid = tid >> 6, lane = tid & 63;

    // S = 512, blockDim = 256 -> 2 elements per thread
    float v0 = sc[tid];
    float v1 = sc[tid + 256];

    // ---- max reduction ----
    float m = fmaxf(v0, v1);
    m = waveReduceMax(m);
    if (lane == 0) red[wid] = m;
    __syncthreads();
    if (tid == 0) red[0] = fmaxf(fmaxf(red[0], red[1]), fmaxf(red[2], red[3]));
    __syncthreads();
    const float rowmax = red[0];
    __syncthreads();

    // ---- exp + sum reduction ----
    float e0 = __expf(v0 - rowmax);
    float e1 = __expf(v1 - rowmax);
    float s = e0 + e1;
    s = waveReduceSum(s);
    if (lane == 0) red[wid] = s;
    __syncthreads();
    if (tid == 0) red[0] = red[0] + red[1] + red[2] + red[3];
    __syncthreads();
    const float inv = 1.0f / red[0];

    // ---- scatter-add (duplicates possible -> atomics) ----
    atomicAdd(&o[tok[tid]],        e0 * inv);
    atomicAdd(&o[tok[tid + 256]],  e1 * inv);
}

extern "C" void kernel_launch(void* const* d_in, const int* in_sizes, int n_in,
                              void* d_out, int out_size, void* d_ws, size_t ws_size,
                              hipStream_t stream) {
    const int*   inputs   = (const int*)d_in[0];    // [B,S]
    const float* enc_out  = (const float*)d_in[1];  // [B,S,H]
    const float* dec_out  = (const float*)d_in[2];  // [B,T,H]
    const float* ibias    = (const float*)d_in[3];  // [B,S]
    const float* W        = (const float*)d_in[4];  // [H,H]
    const float* bproj    = (const float*)d_in[5];  // [H]
    float* out = (float*)d_out;

    const int B = 4, S = 512, T = 256, H = 1024, V = 32000;

    float* enc    = (float*)d_ws;              // B*S*H   = 2M floats (8 MB)
    float* scores = enc + (size_t)B * S * H;   // B*T*S   = 512K floats (2 MB)

    // zero the 131 MB output (harness poisons it before every call)
    hipMemsetAsync(d_out, 0, (size_t)out_size * sizeof(float), stream);

    // K1: enc = tanh(encoder @ W + b)   M=B*S=2048, N=K=H=1024
    dim3 g1(H / TILE, (B * S) / TILE);
    gemm_tanh<<<g1, 256, 0, stream>>>(enc_out, W, bproj, enc, B * S, H, H);

    // K2: scores = dec @ enc^T + bias   per-batch, M=T, N=S, K=H
    dim3 g2(S / TILE, T / TILE, B);
    gemm_nt_bias<<<g2, 256, 0, stream>>>(dec_out, enc, ibias, scores, T, S, H);

    // K3: softmax over S + scatter into vocab
    softmax_scatter<<<B * T, 256, 0, stream>>>(scores, inputs, out, T, S, V);
}

// Round 2
// 247.706 us; speedup vs baseline: 2.1857x; 2.1857x over previous
//
#include <hip/hip_runtime.h>
#include <hip/hip_bf16.h>
#include <math.h>

// Dims fixed by setup_inputs: B=4, S=512, T=256, H=1024, V=32000
typedef __bf16 bf16x8 __attribute__((ext_vector_type(8)));
typedef float  f32x4  __attribute__((ext_vector_type(4)));

__device__ __forceinline__ unsigned short f2bf(float x) {
    unsigned u = __float_as_uint(x);
    u += 0x7fffu + ((u >> 16) & 1u);          // RNE
    return (unsigned short)(u >> 16);
}
__device__ __forceinline__ float bf2f(unsigned short h) {
    return __uint_as_float(((unsigned)h) << 16);
}

// async global->LDS, 16B per lane; LDS dest = wave base + lane*16
__device__ __forceinline__ void gl2lds16(const void* g, void* l) {
    __builtin_amdgcn_global_load_lds(
        (const __attribute__((address_space(1))) unsigned int*)(uintptr_t)g,
        (__attribute__((address_space(3))) unsigned int*)(unsigned int)(uintptr_t)l,
        16, 0, 0);
}

// ---- prep: Wt[n][k] = W[k][n], converted to bf16 hi/lo ----
__global__ __launch_bounds__(256) void transpose_convert(const float* __restrict__ W,
                                                         unsigned short* __restrict__ Wth,
                                                         unsigned short* __restrict__ Wtl) {
    __shared__ float tile[64][65];
    const int k0 = blockIdx.y * 64, n0 = blockIdx.x * 64;
    const int c = threadIdx.x & 63, r0 = threadIdx.x >> 6;
    #pragma unroll
    for (int p = 0; p < 16; ++p) {
        int r = r0 + p * 4;
        tile[r][c] = W[(size_t)(k0 + r) * 1024 + n0 + c];
    }
    __syncthreads();
    #pragma unroll
    for (int p = 0; p < 16; ++p) {
        int rn = r0 + p * 4;                 // n-local
        float v = tile[c][rn];               // = W[k0+c][n0+rn]
        unsigned short h = f2bf(v);
        size_t idx = (size_t)(n0 + rn) * 1024 + k0 + c;
        Wth[idx] = h;
        Wtl[idx] = f2bf(v - bf2f(h));
    }
}

// ---- split-bf16 MFMA GEMM: C[m][n] = epilogue( sum_k A[m][k]*Bt[n][k] + bias[n] )
// A: fp32 [*,K] (converted to hi/lo while staging); Bt: bf16 hi/lo [N,K].
// EPI 0: C fp32 = acc + bias.   EPI 1: tanh(acc+bias) -> bf16 hi/lo arrays.
template <int EPI>
__global__ __launch_bounds__(256) void gemm_bt(
    const float* __restrict__ A,
    const unsigned short* __restrict__ Bh, const unsigned short* __restrict__ Bl,
    const float* __restrict__ bias,
    float* __restrict__ Cf, unsigned short* __restrict__ Ch, unsigned short* __restrict__ Cl,
    int M, int N, int K,
    long long aB, long long bB, long long biasB, long long cB) {

    const int zb = blockIdx.z;
    A    += (size_t)zb * aB;
    Bh   += (size_t)zb * bB;
    Bl   += (size_t)zb * bB;
    bias += (size_t)zb * biasB;

    __shared__ __align__(16) unsigned short sAh[64 * 32];
    __shared__ __align__(16) unsigned short sAl[64 * 32];
    __shared__ __align__(16) unsigned short sBh[64 * 32];
    __shared__ __align__(16) unsigned short sBl[64 * 32];

    const int t = threadIdx.x;
    const int lane = t & 63;
    const int w = t >> 6;
    const int wm = w >> 1, wn = w & 1;
    const int ln15 = lane & 15, q4 = lane >> 4;

    const int row0 = blockIdx.y * 64;
    const int col0 = blockIdx.x * 64;

    f32x4 acc[2][2] = {};

    const int ar = t >> 3, aq = t & 7;   // A stage: row(+32 for pass 1), float4 idx
    const int br = t >> 2, bq = t & 3;   // B stage: row, 16B chunk

    for (int k0 = 0; k0 < K; k0 += 32) {
        // B: async bf16 hi/lo -> LDS (lane-contiguous layout: lds off = t*16B)
        {
            size_t go = (size_t)(col0 + br) * K + k0 + bq * 8;
            gl2lds16(Bh + go, &sBh[t * 8]);
            gl2lds16(Bl + go, &sBl[t * 8]);
        }
        // A: fp32 float4 load, split to hi/lo bf16, LDS write
        #pragma unroll
        for (int p = 0; p < 2; ++p) {
            int r = ar + p * 32;
            const float4 v = *(const float4*)(A + (size_t)(row0 + r) * K + k0 + aq * 4);
            ushort4 h, l;
            h.x = f2bf(v.x); l.x = f2bf(v.x - bf2f(h.x));
            h.y = f2bf(v.y); l.y = f2bf(v.y - bf2f(h.y));
            h.z = f2bf(v.z); l.z = f2bf(v.z - bf2f(h.z));
            h.w = f2bf(v.w); l.w = f2bf(v.w - bf2f(h.w));
            *(ushort4*)&sAh[r * 32 + aq * 4] = h;
            *(ushort4*)&sAl[r * 32 + aq * 4] = l;
        }
        __syncthreads();

        bf16x8 ah[2], al[2], bh[2], bl2[2];
        #pragma unroll
        for (int i = 0; i < 2; ++i) {
            int rr = wm * 32 + i * 16 + ln15;
            ah[i] = *(const bf16x8*)&sAh[rr * 32 + q4 * 8];
            al[i] = *(const bf16x8*)&sAl[rr * 32 + q4 * 8];
        }
        #pragma unroll
        for (int j = 0; j < 2; ++j) {
            int rr = wn * 32 + j * 16 + ln15;
            bh[j]  = *(const bf16x8*)&sBh[rr * 32 + q4 * 8];
            bl2[j] = *(const bf16x8*)&sBl[rr * 32 + q4 * 8];
        }
        #pragma unroll
        for (int i = 0; i < 2; ++i)
            #pragma unroll
            for (int j = 0; j < 2; ++j) {
                acc[i][j] = __builtin_amdgcn_mfma_f32_16x16x32_bf16(ah[i], bh[j],  acc[i][j], 0, 0, 0);
                acc[i][j] = __builtin_amdgcn_mfma_f32_16x16x32_bf16(ah[i], bl2[j], acc[i][j], 0, 0, 0);
                acc[i][j] = __builtin_amdgcn_mfma_f32_16x16x32_bf16(al[i], bh[j],  acc[i][j], 0, 0, 0);
            }
        __syncthreads();
    }

    // epilogue: C layout col=lane&15, row=(lane>>4)*4+reg
    #pragma unroll
    for (int i = 0; i < 2; ++i)
        #pragma unroll
        for (int j = 0; j < 2; ++j) {
            int colg = col0 + wn * 32 + j * 16 + ln15;
            float bv = bias[colg];
            #pragma unroll
            for (int r = 0; r < 4; ++r) {
                int rowg = row0 + wm * 32 + i * 16 + q4 * 4 + r;
                float v = acc[i][j][r] + bv;
                if (EPI == 0) {
                    Cf[(size_t)zb * cB + (size_t)rowg * N + colg] = v;
                } else {
                    float tv = tanhf(v);
                    unsigned short h = f2bf(tv);
                    size_t idx = (size_t)zb * cB + (size_t)rowg * N + colg;
                    Ch[idx] = h;
                    Cl[idx] = f2bf(tv - bf2f(h));
                }
            }
        }
}

// ---- fused: softmax over S, zero the vocab row, scatter-add ----
__inline__ __device__ float waveReduceMax(float v) {
    #pragma unroll
    for (int off = 32; off > 0; off >>= 1) v = fmaxf(v, __shfl_down(v, off));
    return v;
}
__inline__ __device__ float waveReduceSum(float v) {
    #pragma unroll
    for (int off = 32; off > 0; off >>= 1) v += __shfl_down(v, off);
    return v;
}

__global__ __launch_bounds__(256) void softmax_scatter(const float* __restrict__ scores,
                                                       const int* __restrict__ tokens,
                                                       float* __restrict__ out) {
    const int row = blockIdx.x;          // b*T + t
    const int b = row >> 8;              // T = 256
    const float* sc = scores + (size_t)row * 512;
    const int* tok = tokens + (size_t)b * 512;
    float* o = out + (size_t)row * 32000;

    __shared__ float red[4];
    const int tid = threadIdx.x;
    const int wid = tid >> 6, lane = tid & 63;

    float v0 = sc[tid];
    float v1 = sc[tid + 256];

    float m = fmaxf(v0, v1);
    m = waveReduceMax(m);
    if (lane == 0) red[wid] = m;
    __syncthreads();
    if (tid == 0) red[0] = fmaxf(fmaxf(red[0], red[1]), fmaxf(red[2], red[3]));
    __syncthreads();
    const float rowmax = red[0];
    __syncthreads();

    float e0 = __expf(v0 - rowmax);
    float e1 = __expf(v1 - rowmax);
    float s = e0 + e1;
    s = waveReduceSum(s);
    if (lane == 0) red[wid] = s;
    __syncthreads();
    if (tid == 0) red[0] = red[0] + red[1] + red[2] + red[3];
    __syncthreads();
    const float inv = 1.0f / red[0];

    // zero this row's 32000 vocab slots (row exclusive to this block)
    float4 z = make_float4(0.f, 0.f, 0.f, 0.f);
    float4* o4 = (float4*)o;
    for (int i = tid; i < 8000; i += 256) o4[i] = z;

    __threadfence_block();
    __syncthreads();

    atomicAdd(&o[tok[tid]],       e0 * inv);
    atomicAdd(&o[tok[tid + 256]], e1 * inv);
}

extern "C" void kernel_launch(void* const* d_in, const int* in_sizes, int n_in,
                              void* d_out, int out_size, void* d_ws, size_t ws_size,
                              hipStream_t stream) {
    const int*   inputs  = (const int*)d_in[0];    // [B,S]
    const float* enc_in  = (const float*)d_in[1];  // [B,S,H] = [2048,1024]
    const float* dec_in  = (const float*)d_in[2];  // [B,T,H] = [1024,1024]
    const float* ibias   = (const float*)d_in[3];  // [B,S]
    const float* W       = (const float*)d_in[4];  // [H,H]
    const float* bproj   = (const float*)d_in[5];  // [H]
    float* out = (float*)d_out;

    // ws: enc hi (4MB) | enc lo (4MB) | scores (2MB)  == 10 MB
    unsigned short* ench = (unsigned short*)d_ws;
    unsigned short* encl = ench + (size_t)2048 * 1024;
    float* scores = (float*)(encl + (size_t)2048 * 1024);

    // W^T hi/lo live in the tail of d_out (dead until scatter re-zeroes it)
    size_t outBytes = (size_t)out_size * sizeof(float);
    unsigned short* Wth = (unsigned short*)((char*)d_out + outBytes - (size_t)4 * 1024 * 1024);
    unsigned short* Wtl = Wth + (size_t)1024 * 1024;

    // 1) transpose+convert W -> Wt hi/lo [N,K]
    transpose_convert<<<dim3(16, 16), 256, 0, stream>>>(W, Wth, Wtl);

    // 2) enc = tanh(enc_in @ W + bproj) -> bf16 hi/lo   M=2048,N=1024,K=1024
    gemm_bt<1><<<dim3(16, 32, 1), 256, 0, stream>>>(
        enc_in, Wth, Wtl, bproj, nullptr, ench, encl,
        2048, 1024, 1024, 0LL, 0LL, 0LL, 0LL);

    // 3) scores[b] = dec[b] @ enc[b]^T + ibias[b]   per batch M=256,N=512,K=1024
    gemm_bt<0><<<dim3(8, 4, 4), 256, 0, stream>>>(
        dec_in, ench, encl, ibias, scores, nullptr, nullptr,
        256, 512, 1024,
        (long long)256 * 1024, (long long)512 * 1024, 512LL, (long long)256 * 512);

    // 4) softmax over S + zero vocab row + scatter-add
    softmax_scatter<<<dim3(4 * 256), 256, 0, stream>>>(scores, inputs, out);
}

// Round 3
// 209.668 us; speedup vs baseline: 2.5822x; 1.1814x over previous
//
#include <hip/hip_runtime.h>
#include <hip/hip_bf16.h>
#include <math.h>

// Dims fixed by setup_inputs: B=4, S=512, T=256, H=1024, V=32000
typedef __bf16 bf16x8 __attribute__((ext_vector_type(8)));
typedef float  f32x4  __attribute__((ext_vector_type(4)));

__device__ __forceinline__ unsigned short f2bf(float x) {
    unsigned u = __float_as_uint(x);
    u += 0x7fffu + ((u >> 16) & 1u);          // RNE
    return (unsigned short)(u >> 16);
}
__device__ __forceinline__ float bf2f(unsigned short h) {
    return __uint_as_float(((unsigned)h) << 16);
}

// async global->LDS, 16B per lane; LDS dest = wave-uniform base + lane*16
__device__ __forceinline__ void gl2lds16(const void* g, void* l) {
    __builtin_amdgcn_global_load_lds(
        (const __attribute__((address_space(1))) unsigned int*)(uintptr_t)g,
        (__attribute__((address_space(3))) unsigned int*)(unsigned int)(uintptr_t)l,
        16, 0, 0);
}

// ---- prep A: flat fp32 -> bf16 hi/lo (enc_in then dec_in selected by block) ----
__global__ __launch_bounds__(256) void convert_split(const float* __restrict__ encf,
                                                     unsigned short* __restrict__ eh,
                                                     unsigned short* __restrict__ el,
                                                     const float* __restrict__ decf,
                                                     unsigned short* __restrict__ dh,
                                                     unsigned short* __restrict__ dl) {
    const int bid = blockIdx.x;
    const float* src; unsigned short *ph, *pl; int i;
    if (bid < 2048) { src = encf; ph = eh; pl = el; i = bid * 256 + threadIdx.x; }
    else            { src = decf; ph = dh; pl = dl; i = (bid - 2048) * 256 + threadIdx.x; }
    const float4 v = ((const float4*)src)[i];
    ushort4 h, l;
    h.x = f2bf(v.x); l.x = f2bf(v.x - bf2f(h.x));
    h.y = f2bf(v.y); l.y = f2bf(v.y - bf2f(h.y));
    h.z = f2bf(v.z); l.z = f2bf(v.z - bf2f(h.z));
    h.w = f2bf(v.w); l.w = f2bf(v.w - bf2f(h.w));
    ((ushort4*)ph)[i] = h;
    ((ushort4*)pl)[i] = l;
}

// ---- prep W: Wt[n][k] = W[k][n], bf16 hi/lo ----
__global__ __launch_bounds__(256) void transpose_convert(const float* __restrict__ W,
                                                         unsigned short* __restrict__ Wth,
                                                         unsigned short* __restrict__ Wtl) {
    __shared__ float tile[64][65];
    const int k0 = blockIdx.y * 64, n0 = blockIdx.x * 64;
    const int c = threadIdx.x & 63, r0 = threadIdx.x >> 6;
    #pragma unroll
    for (int p = 0; p < 16; ++p) {
        int r = r0 + p * 4;
        tile[r][c] = W[(size_t)(k0 + r) * 1024 + n0 + c];
    }
    __syncthreads();
    #pragma unroll
    for (int p = 0; p < 16; ++p) {
        int rn = r0 + p * 4;
        float v = tile[c][rn];               // = W[k0+c][n0+rn]
        unsigned short h = f2bf(v);
        size_t idx = (size_t)(n0 + rn) * 1024 + k0 + c;
        Wth[idx] = h;
        Wtl[idx] = f2bf(v - bf2f(h));
    }
}

// ---- split-bf16 MFMA GEMM, all operands pre-split bf16 hi/lo, B transposed [N][K].
// Tile 64x64, BK=64, all staging via global_load_lds(16B), XOR-swizzled LDS k-chunks.
// EPI 0: Cf = acc (no bias; split-K partial). EPI 1: tanh(acc+bias[n]) -> Ch/Cl.
template <int EPI>
__global__ __launch_bounds__(256) void gemm_bt(
    const unsigned short* __restrict__ Ah, const unsigned short* __restrict__ Al,
    const unsigned short* __restrict__ Bh, const unsigned short* __restrict__ Bl,
    const float* __restrict__ bias,
    float* __restrict__ Cf, unsigned short* __restrict__ Ch, unsigned short* __restrict__ Cl,
    int N, int K, int kIter, int ksplit,
    long long aBatch, long long bBatch, long long cBatch, long long cPart) {

    const int z = blockIdx.z;
    const int batch = z / ksplit;
    const int ks = z - batch * ksplit;
    Ah += (size_t)batch * aBatch;  Al += (size_t)batch * aBatch;
    Bh += (size_t)batch * bBatch;  Bl += (size_t)batch * bBatch;
    const int kOff = ks * kIter * 64;

    __shared__ __align__(16) unsigned short sAh[64 * 64];
    __shared__ __align__(16) unsigned short sAl[64 * 64];
    __shared__ __align__(16) unsigned short sBh[64 * 64];
    __shared__ __align__(16) unsigned short sBl[64 * 64];

    const int t = threadIdx.x;
    const int lane = t & 63;
    const int w = t >> 6;
    const int wm = w >> 1, wn = w & 1;
    const int ln15 = lane & 15, q4 = lane >> 4;

    const int row0 = blockIdx.y * 64;
    const int col0 = blockIdx.x * 64;

    // staging: 512 16B-chunks; wave w call p covers chunks c = w*128 + p*64 + lane.
    // LDS chunk (r, ch) holds global k-chunk (ch ^ (r&7))  [bank swizzle]
    const int c0 = w * 128 + lane;
    const int r0s = c0 >> 3, g0 = ((c0 & 7) ^ (r0s & 7)) * 8;
    const int c1 = c0 + 64;
    const int r1s = c1 >> 3, g1 = ((c1 & 7) ^ (r1s & 7)) * 8;
    const size_t a0 = (size_t)(row0 + r0s) * K + kOff + g0;
    const size_t a1 = (size_t)(row0 + r1s) * K + kOff + g1;
    const size_t b0 = (size_t)(col0 + r0s) * K + kOff + g0;
    const size_t b1 = (size_t)(col0 + r1s) * K + kOff + g1;

    f32x4 acc[2][2] = {};

    for (int kk = 0; kk < kIter; ++kk) {
        const int k0 = kk * 64;
        gl2lds16(Ah + a0 + k0, &sAh[c0 * 8]);
        gl2lds16(Ah + a1 + k0, &sAh[c1 * 8]);
        gl2lds16(Al + a0 + k0, &sAl[c0 * 8]);
        gl2lds16(Al + a1 + k0, &sAl[c1 * 8]);
        gl2lds16(Bh + b0 + k0, &sBh[c0 * 8]);
        gl2lds16(Bh + b1 + k0, &sBh[c1 * 8]);
        gl2lds16(Bl + b0 + k0, &sBl[c0 * 8]);
        gl2lds16(Bl + b1 + k0, &sBl[c1 * 8]);
        __syncthreads();

        #pragma unroll
        for (int kh = 0; kh < 2; ++kh) {
            bf16x8 ah[2], al[2], bh[2], bl[2];
            #pragma unroll
            for (int i = 0; i < 2; ++i) {
                int rr = wm * 32 + i * 16 + ln15;
                int off = rr * 64 + (((kh * 4 + q4) ^ (rr & 7)) * 8);
                ah[i] = *(const bf16x8*)&sAh[off];
                al[i] = *(const bf16x8*)&sAl[off];
            }
            #pragma unroll
            for (int j = 0; j < 2; ++j) {
                int rr = wn * 32 + j * 16 + ln15;
                int off = rr * 64 + (((kh * 4 + q4) ^ (rr & 7)) * 8);
                bh[j] = *(const bf16x8*)&sBh[off];
                bl[j] = *(const bf16x8*)&sBl[off];
            }
            #pragma unroll
            for (int i = 0; i < 2; ++i)
                #pragma unroll
                for (int j = 0; j < 2; ++j) {
                    acc[i][j] = __builtin_amdgcn_mfma_f32_16x16x32_bf16(ah[i], bh[j], acc[i][j], 0, 0, 0);
                    acc[i][j] = __builtin_amdgcn_mfma_f32_16x16x32_bf16(ah[i], bl[j], acc[i][j], 0, 0, 0);
                    acc[i][j] = __builtin_amdgcn_mfma_f32_16x16x32_bf16(al[i], bh[j], acc[i][j], 0, 0, 0);
                }
        }
        __syncthreads();
    }

    // epilogue: C layout col=lane&15, row=(lane>>4)*4+reg
    float* outp = Cf + (size_t)batch * cBatch + (size_t)ks * cPart;
    #pragma unroll
    for (int i = 0; i < 2; ++i)
        #pragma unroll
        for (int j = 0; j < 2; ++j) {
            int colg = col0 + wn * 32 + j * 16 + ln15;
            #pragma unroll
            for (int r = 0; r < 4; ++r) {
                int rowg = row0 + wm * 32 + i * 16 + q4 * 4 + r;
                if (EPI == 0) {
                    outp[(size_t)rowg * N + colg] = acc[i][j][r];
                } else {
                    float tv = tanhf(acc[i][j][r] + bias[colg]);
                    unsigned short h = f2bf(tv);
                    size_t idx = (size_t)rowg * N + colg;
                    Ch[idx] = h;
                    Cl[idx] = f2bf(tv - bf2f(h));
                }
            }
        }
}

// ---- fused: sum split-K parts + bias, softmax over S, zero vocab row, scatter ----
__inline__ __device__ float waveReduceMax(float v) {
    #pragma unroll
    for (int off = 32; off > 0; off >>= 1) v = fmaxf(v, __shfl_down(v, off));
    return v;
}
__inline__ __device__ float waveReduceSum(float v) {
    #pragma unroll
    for (int off = 32; off > 0; off >>= 1) v += __shfl_down(v, off);
    return v;
}

__global__ __launch_bounds__(256) void softmax_scatter(const float* __restrict__ scores,
                                                       const int* __restrict__ tokens,
                                                       const float* __restrict__ ibias,
                                                       float* __restrict__ out) {
    const int row = blockIdx.x;          // b*T + t
    const int b = row >> 8;              // T = 256
    const float* s0 = scores + (size_t)row * 512;
    const float* s1 = s0 + (size_t)4 * 256 * 512;   // second split-K partial
    const float* bi = ibias + (size_t)b * 512;
    const int* tok = tokens + (size_t)b * 512;
    float* o = out + (size_t)row * 32000;

    __shared__ float red[4];
    const int tid = threadIdx.x;
    const int wid = tid >> 6, lane = tid & 63;

    float v0 = s0[tid]       + s1[tid]       + bi[tid];
    float v1 = s0[tid + 256] + s1[tid + 256] + bi[tid + 256];

    float m = fmaxf(v0, v1);
    m = waveReduceMax(m);
    if (lane == 0) red[wid] = m;
    __syncthreads();
    if (tid == 0) red[0] = fmaxf(fmaxf(red[0], red[1]), fmaxf(red[2], red[3]));
    __syncthreads();
    const float rowmax = red[0];
    __syncthreads();

    float e0 = __expf(v0 - rowmax);
    float e1 = __expf(v1 - rowmax);
    float s = e0 + e1;
    s = waveReduceSum(s);
    if (lane == 0) red[wid] = s;
    __syncthreads();
    if (tid == 0) red[0] = red[0] + red[1] + red[2] + red[3];
    __syncthreads();
    const float inv = 1.0f / red[0];

    // zero this row's 32000 vocab slots (row exclusive to this block)
    float4 z = make_float4(0.f, 0.f, 0.f, 0.f);
    float4* o4 = (float4*)o;
    for (int i = tid; i < 8000; i += 256) o4[i] = z;

    __threadfence_block();
    __syncthreads();

    atomicAdd(&o[tok[tid]],       e0 * inv);
    atomicAdd(&o[tok[tid + 256]], e1 * inv);
}

extern "C" void kernel_launch(void* const* d_in, const int* in_sizes, int n_in,
                              void* d_out, int out_size, void* d_ws, size_t ws_size,
                              hipStream_t stream) {
    const int*   inputs  = (const int*)d_in[0];    // [B,S]
    const float* enc_in  = (const float*)d_in[1];  // [2048,1024]
    const float* dec_in  = (const float*)d_in[2];  // [1024,1024]
    const float* ibias   = (const float*)d_in[3];  // [B,S]
    const float* W       = (const float*)d_in[4];  // [1024,1024]
    const float* bproj   = (const float*)d_in[5];  // [1024]
    float* out = (float*)d_out;

    // scores split-K partials (must survive into scatter) live in ws: 4 MB
    float* scores = (float*)d_ws;                  // 2 x [4,256,512]

    // all other intermediates live in the dead tail of d_out (zeroed by scatter last)
    size_t outBytes = (size_t)out_size * sizeof(float);
    unsigned short* tail = (unsigned short*)((char*)d_out + outBytes - (size_t)24 * 1024 * 1024);
    unsigned short* Aeh = tail;                         // enc_in hi  [2048,1024]
    unsigned short* Ael = Aeh + (size_t)2048 * 1024;    // enc_in lo
    unsigned short* Dh  = Ael + (size_t)2048 * 1024;    // dec hi     [1024,1024]
    unsigned short* Dl  = Dh  + (size_t)1024 * 1024;
    unsigned short* Wth = Dl  + (size_t)1024 * 1024;    // W^T hi     [1024,1024]
    unsigned short* Wtl = Wth + (size_t)1024 * 1024;
    unsigned short* ench = Wtl + (size_t)1024 * 1024;   // tanh out hi [2048,1024]
    unsigned short* encl = ench + (size_t)2048 * 1024;

    // 1) split-convert enc_in + dec_in
    convert_split<<<dim3(3072), 256, 0, stream>>>(enc_in, Aeh, Ael, dec_in, Dh, Dl);

    // 2) transpose+convert W
    transpose_convert<<<dim3(16, 16), 256, 0, stream>>>(W, Wth, Wtl);

    // 3) enc = tanh(enc_in @ W + bproj) -> bf16 hi/lo   M=2048,N=1024,K=1024
    gemm_bt<1><<<dim3(16, 32, 1), 256, 0, stream>>>(
        Aeh, Ael, Wth, Wtl, bproj, nullptr, ench, encl,
        1024, 1024, 16, 1, 0LL, 0LL, 0LL, 0LL);

    // 4) scores[b] = dec[b] @ enc[b]^T   per batch M=256,N=512,K=1024, split-K=2
    gemm_bt<0><<<dim3(8, 4, 8), 256, 0, stream>>>(
        Dh, Dl, ench, encl, nullptr, scores, nullptr, nullptr,
        512, 1024, 8, 2,
        (long long)256 * 1024, (long long)512 * 1024,
        (long long)256 * 512, (long long)4 * 256 * 512);

    // 5) sum parts + bias, softmax over S, zero vocab row, scatter-add
    softmax_scatter<<<dim3(4 * 256), 256, 0, stream>>>(scores, inputs, ibias, out);
}

// Round 4
// 209.386 us; speedup vs baseline: 2.5857x; 1.0013x over previous
//
#include <hip/hip_runtime.h>
#include <hip/hip_bf16.h>
#include <math.h>

// Dims fixed by setup_inputs: B=4, S=512, T=256, H=1024, V=32000
typedef __bf16 bf16x8 __attribute__((ext_vector_type(8)));
typedef float  f32x4  __attribute__((ext_vector_type(4)));

__device__ __forceinline__ unsigned short f2bf(float x) {
    unsigned u = __float_as_uint(x);
    u += 0x7fffu + ((u >> 16) & 1u);          // RNE
    return (unsigned short)(u >> 16);
}
__device__ __forceinline__ float bf2f(unsigned short h) {
    return __uint_as_float(((unsigned)h) << 16);
}

// async global->LDS, 16B per lane; LDS dest = wave-uniform base + lane*16
__device__ __forceinline__ void gl2lds16(const void* g, void* l) {
    __builtin_amdgcn_global_load_lds(
        (const __attribute__((address_space(1))) unsigned int*)(uintptr_t)g,
        (__attribute__((address_space(3))) unsigned int*)(unsigned int)(uintptr_t)l,
        16, 0, 0);
}

// ---- prep A: flat fp32 -> bf16 hi/lo (enc_in then dec_in selected by block) ----
__global__ __launch_bounds__(256) void convert_split(const float* __restrict__ encf,
                                                     unsigned short* __restrict__ eh,
                                                     unsigned short* __restrict__ el,
                                                     const float* __restrict__ decf,
                                                     unsigned short* __restrict__ dh,
                                                     unsigned short* __restrict__ dl) {
    const int bid = blockIdx.x;
    const float* src; unsigned short *ph, *pl; int i;
    if (bid < 2048) { src = encf; ph = eh; pl = el; i = bid * 256 + threadIdx.x; }
    else            { src = decf; ph = dh; pl = dl; i = (bid - 2048) * 256 + threadIdx.x; }
    const float4 v = ((const float4*)src)[i];
    ushort4 h, l;
    h.x = f2bf(v.x); l.x = f2bf(v.x - bf2f(h.x));
    h.y = f2bf(v.y); l.y = f2bf(v.y - bf2f(h.y));
    h.z = f2bf(v.z); l.z = f2bf(v.z - bf2f(h.z));
    h.w = f2bf(v.w); l.w = f2bf(v.w - bf2f(h.w));
    ((ushort4*)ph)[i] = h;
    ((ushort4*)pl)[i] = l;
}

// ---- prep W: Wt[n][k] = W[k][n], bf16 hi/lo ----
__global__ __launch_bounds__(256) void transpose_convert(const float* __restrict__ W,
                                                         unsigned short* __restrict__ Wth,
                                                         unsigned short* __restrict__ Wtl) {
    __shared__ float tile[64][65];
    const int k0 = blockIdx.y * 64, n0 = blockIdx.x * 64;
    const int c = threadIdx.x & 63, r0 = threadIdx.x >> 6;
    #pragma unroll
    for (int p = 0; p < 16; ++p) {
        int r = r0 + p * 4;
        tile[r][c] = W[(size_t)(k0 + r) * 1024 + n0 + c];
    }
    __syncthreads();
    #pragma unroll
    for (int p = 0; p < 16; ++p) {
        int rn = r0 + p * 4;
        float v = tile[c][rn];               // = W[k0+c][n0+rn]
        unsigned short h = f2bf(v);
        size_t idx = (size_t)(n0 + rn) * 1024 + k0 + c;
        Wth[idx] = h;
        Wtl[idx] = f2bf(v - bf2f(h));
    }
}

// ---- split-bf16 MFMA GEMM, operands pre-split bf16 hi/lo, B transposed [N][K].
// Tile 64x64, BK=64, all staging via global_load_lds(16B), XOR-swizzled LDS k-chunks.
// Writes raw fp32 partial sums (split-K); bias/activation applied downstream.
__global__ __launch_bounds__(256, 4) void gemm_bt(
    const unsigned short* __restrict__ Ah, const unsigned short* __restrict__ Al,
    const unsigned short* __restrict__ Bh, const unsigned short* __restrict__ Bl,
    float* __restrict__ Cf,
    int N, int K, int kIter, int ksplit,
    long long aBatch, long long bBatch, long long cBatch, long long cPart) {

    const int z = blockIdx.z;
    const int batch = z / ksplit;
    const int ks = z - batch * ksplit;
    Ah += (size_t)batch * aBatch;  Al += (size_t)batch * aBatch;
    Bh += (size_t)batch * bBatch;  Bl += (size_t)batch * bBatch;
    const int kOff = ks * kIter * 64;

    __shared__ __align__(16) unsigned short sAh[64 * 64];
    __shared__ __align__(16) unsigned short sAl[64 * 64];
    __shared__ __align__(16) unsigned short sBh[64 * 64];
    __shared__ __align__(16) unsigned short sBl[64 * 64];

    const int t = threadIdx.x;
    const int lane = t & 63;
    const int w = t >> 6;
    const int wm = w >> 1, wn = w & 1;
    const int ln15 = lane & 15, q4 = lane >> 4;

    const int row0 = blockIdx.y * 64;
    const int col0 = blockIdx.x * 64;

    // staging: 512 16B-chunks; wave w call p covers chunks c = w*128 + p*64 + lane.
    // LDS chunk (r, ch) holds global k-chunk (ch ^ (r&7))  [bank swizzle]
    const int c0 = w * 128 + lane;
    const int r0s = c0 >> 3, g0 = ((c0 & 7) ^ (r0s & 7)) * 8;
    const int c1 = c0 + 64;
    const int r1s = c1 >> 3, g1 = ((c1 & 7) ^ (r1s & 7)) * 8;
    const size_t a0 = (size_t)(row0 + r0s) * K + kOff + g0;
    const size_t a1 = (size_t)(row0 + r1s) * K + kOff + g1;
    const size_t b0 = (size_t)(col0 + r0s) * K + kOff + g0;
    const size_t b1 = (size_t)(col0 + r1s) * K + kOff + g1;

    f32x4 acc[2][2] = {};

    for (int kk = 0; kk < kIter; ++kk) {
        const int k0 = kk * 64;
        gl2lds16(Ah + a0 + k0, &sAh[c0 * 8]);
        gl2lds16(Ah + a1 + k0, &sAh[c1 * 8]);
        gl2lds16(Al + a0 + k0, &sAl[c0 * 8]);
        gl2lds16(Al + a1 + k0, &sAl[c1 * 8]);
        gl2lds16(Bh + b0 + k0, &sBh[c0 * 8]);
        gl2lds16(Bh + b1 + k0, &sBh[c1 * 8]);
        gl2lds16(Bl + b0 + k0, &sBl[c0 * 8]);
        gl2lds16(Bl + b1 + k0, &sBl[c1 * 8]);
        __syncthreads();

        #pragma unroll
        for (int kh = 0; kh < 2; ++kh) {
            bf16x8 ah[2], al[2], bh[2], bl[2];
            #pragma unroll
            for (int i = 0; i < 2; ++i) {
                int rr = wm * 32 + i * 16 + ln15;
                int off = rr * 64 + (((kh * 4 + q4) ^ (rr & 7)) * 8);
                ah[i] = *(const bf16x8*)&sAh[off];
                al[i] = *(const bf16x8*)&sAl[off];
            }
            #pragma unroll
            for (int j = 0; j < 2; ++j) {
                int rr = wn * 32 + j * 16 + ln15;
                int off = rr * 64 + (((kh * 4 + q4) ^ (rr & 7)) * 8);
                bh[j] = *(const bf16x8*)&sBh[off];
                bl[j] = *(const bf16x8*)&sBl[off];
            }
            #pragma unroll
            for (int i = 0; i < 2; ++i)
                #pragma unroll
                for (int j = 0; j < 2; ++j) {
                    acc[i][j] = __builtin_amdgcn_mfma_f32_16x16x32_bf16(ah[i], bh[j], acc[i][j], 0, 0, 0);
                    acc[i][j] = __builtin_amdgcn_mfma_f32_16x16x32_bf16(ah[i], bl[j], acc[i][j], 0, 0, 0);
                    acc[i][j] = __builtin_amdgcn_mfma_f32_16x16x32_bf16(al[i], bh[j], acc[i][j], 0, 0, 0);
                }
        }
        __syncthreads();
    }

    // epilogue: C layout col=lane&15, row=(lane>>4)*4+reg
    float* outp = Cf + (size_t)batch * cBatch + (size_t)ks * cPart;
    #pragma unroll
    for (int i = 0; i < 2; ++i)
        #pragma unroll
        for (int j = 0; j < 2; ++j) {
            int colg = col0 + wn * 32 + j * 16 + ln15;
            #pragma unroll
            for (int r = 0; r < 4; ++r) {
                int rowg = row0 + wm * 32 + i * 16 + q4 * 4 + r;
                outp[(size_t)rowg * N + colg] = acc[i][j][r];
            }
        }
}

// ---- combine gemm1 split-K partials: enc = tanh(P0+P1+bias) -> bf16 hi/lo ----
__global__ __launch_bounds__(256) void tanh_combine(const float* __restrict__ P0,
                                                    const float* __restrict__ P1,
                                                    const float* __restrict__ bias,
                                                    unsigned short* __restrict__ Ch,
                                                    unsigned short* __restrict__ Cl) {
    const int i = blockIdx.x * 256 + threadIdx.x;       // float4 index, [0, 524288)
    const float4 p0 = ((const float4*)P0)[i];
    const float4 p1 = ((const float4*)P1)[i];
    const float4 bv = ((const float4*)bias)[i & 255];   // 1024 cols / 4
    float4 v;
    v.x = tanhf(p0.x + p1.x + bv.x);
    v.y = tanhf(p0.y + p1.y + bv.y);
    v.z = tanhf(p0.z + p1.z + bv.z);
    v.w = tanhf(p0.w + p1.w + bv.w);
    ushort4 h, l;
    h.x = f2bf(v.x); l.x = f2bf(v.x - bf2f(h.x));
    h.y = f2bf(v.y); l.y = f2bf(v.y - bf2f(h.y));
    h.z = f2bf(v.z); l.z = f2bf(v.z - bf2f(h.z));
    h.w = f2bf(v.w); l.w = f2bf(v.w - bf2f(h.w));
    ((ushort4*)Ch)[i] = h;
    ((ushort4*)Cl)[i] = l;
}

// ---- fused: sum 4 split-K parts + bias, softmax over S, zero vocab row, scatter ----
__inline__ __device__ float waveReduceMax(float v) {
    #pragma unroll
    for (int off = 32; off > 0; off >>= 1) v = fmaxf(v, __shfl_down(v, off));
    return v;
}
__inline__ __device__ float waveReduceSum(float v) {
    #pragma unroll
    for (int off = 32; off > 0; off >>= 1) v += __shfl_down(v, off);
    return v;
}

__global__ __launch_bounds__(256) void softmax_scatter(const float* __restrict__ scores,
                                                       const int* __restrict__ tokens,
                                                       const float* __restrict__ ibias,
                                                       float* __restrict__ out) {
    const int row = blockIdx.x;          // b*T + t
    const int b = row >> 8;              // T = 256
    const size_t plane = (size_t)4 * 256 * 512;
    const float* s0 = scores + (size_t)row * 512;
    const float* bi = ibias + (size_t)b * 512;
    const int* tok = tokens + (size_t)b * 512;
    float* o = out + (size_t)row * 32000;

    __shared__ float red[4];
    const int tid = threadIdx.x;
    const int wid = tid >> 6, lane = tid & 63;

    float v0 = bi[tid], v1 = bi[tid + 256];
    #pragma unroll
    for (int p = 0; p < 4; ++p) {
        v0 += s0[p * plane + tid];
        v1 += s0[p * plane + tid + 256];
    }

    float m = fmaxf(v0, v1);
    m = waveReduceMax(m);
    if (lane == 0) red[wid] = m;
    __syncthreads();
    if (tid == 0) red[0] = fmaxf(fmaxf(red[0], red[1]), fmaxf(red[2], red[3]));
    __syncthreads();
    const float rowmax = red[0];
    __syncthreads();

    float e0 = __expf(v0 - rowmax);
    float e1 = __expf(v1 - rowmax);
    float s = e0 + e1;
    s = waveReduceSum(s);
    if (lane == 0) red[wid] = s;
    __syncthreads();
    if (tid == 0) red[0] = red[0] + red[1] + red[2] + red[3];
    __syncthreads();
    const float inv = 1.0f / red[0];

    // zero this row's 32000 vocab slots (row exclusive to this block)
    float4 z = make_float4(0.f, 0.f, 0.f, 0.f);
    float4* o4 = (float4*)o;
    for (int i = tid; i < 8000; i += 256) o4[i] = z;

    __threadfence_block();
    __syncthreads();

    atomicAdd(&o[tok[tid]],       e0 * inv);
    atomicAdd(&o[tok[tid + 256]], e1 * inv);
}

extern "C" void kernel_launch(void* const* d_in, const int* in_sizes, int n_in,
                              void* d_out, int out_size, void* d_ws, size_t ws_size,
                              hipStream_t stream) {
    const int*   inputs  = (const int*)d_in[0];    // [B,S]
    const float* enc_in  = (const float*)d_in[1];  // [2048,1024]
    const float* dec_in  = (const float*)d_in[2];  // [1024,1024]
    const float* ibias   = (const float*)d_in[3];  // [B,S]
    const float* W       = (const float*)d_in[4];  // [1024,1024]
    const float* bproj   = (const float*)d_in[5];  // [1024]
    float* out = (float*)d_out;

    // scores split-K partials (read by scatter while d_out is being zeroed) -> ws: 8 MB
    float* scores = (float*)d_ws;                  // 4 x [4,256,512] fp32

    // all other intermediates live in the dead tail of d_out (zeroed by scatter last)
    size_t outBytes = (size_t)out_size * sizeof(float);
    char* tail = (char*)d_out + outBytes - (size_t)40 * 1024 * 1024;
    unsigned short* Aeh = (unsigned short*)tail;        // enc_in hi  [2048,1024]
    unsigned short* Ael = Aeh + (size_t)2048 * 1024;    // enc_in lo
    unsigned short* Dh  = Ael + (size_t)2048 * 1024;    // dec hi     [1024,1024]
    unsigned short* Dl  = Dh  + (size_t)1024 * 1024;
    unsigned short* Wth = Dl  + (size_t)1024 * 1024;    // W^T hi     [1024,1024]
    unsigned short* Wtl = Wth + (size_t)1024 * 1024;
    unsigned short* ench = Wtl + (size_t)1024 * 1024;   // tanh out hi [2048,1024]
    unsigned short* encl = ench + (size_t)2048 * 1024;
    float* P0 = (float*)(encl + (size_t)2048 * 1024);   // gemm1 partials, 2 x 8 MB
    float* P1 = P0 + (size_t)2048 * 1024;

    // 1) split-convert enc_in + dec_in
    convert_split<<<dim3(3072), 256, 0, stream>>>(enc_in, Aeh, Ael, dec_in, Dh, Dl);

    // 2) transpose+convert W
    transpose_convert<<<dim3(16, 16), 256, 0, stream>>>(W, Wth, Wtl);

    // 3) enc_in @ W partials   M=2048,N=1024,K=1024, split-K=2 -> 1024 blocks (4/CU)
    gemm_bt<<<dim3(16, 32, 2), 256, 0, stream>>>(
        Aeh, Ael, Wth, Wtl, P0,
        1024, 1024, 8, 2, 0LL, 0LL, 0LL, (long long)2048 * 1024);

    // 4) enc = tanh(P0+P1+bproj) -> bf16 hi/lo
    tanh_combine<<<dim3(2048), 256, 0, stream>>>(P0, P1, bproj, ench, encl);

    // 5) scores[b] = dec[b] @ enc[b]^T   per batch M=256,N=512,K=1024, split-K=4 -> 512 blocks
    gemm_bt<<<dim3(8, 4, 16), 256, 0, stream>>>(
        Dh, Dl, ench, encl, scores,
        512, 1024, 4, 4,
        (long long)256 * 1024, (long long)512 * 1024,
        (long long)256 * 512, (long long)4 * 256 * 512);

    // 6) sum parts + bias, softmax over S, zero vocab row, scatter-add
    softmax_scatter<<<dim3(4 * 256), 256, 0, stream>>>(scores, inputs, ibias, out);
}